// Round 3
// baseline (195.517 us; speedup 1.0000x reference)
//
#include <hip/hip_runtime.h>
#include <hip/hip_bf16.h>

typedef __bf16 bf16x8 __attribute__((ext_vector_type(8)));
typedef float  f32x4  __attribute__((ext_vector_type(4)));

#define NEG_BIG (-1e10f)

constexpr int FUSED_N = 4 * 32 * 32 * 256;  // 1048576

// ---------------------------------------------------------------------------
// fp32 inputs, no fp32 MFMA on CDNA4: split x = hi + lo (bf16 RNE + residual),
// scores ~= Ah*Bh + Ah*Bl + Al*Bh (drop lo*lo, ~2^-18 rel). Verified r2.
// ---------------------------------------------------------------------------

// 16B-granule XOR swizzles (conflict-free staging + MFMA b128 reads).
__device__ __forceinline__ int swz16(int row, int g) {
    return (row * 16 + (g ^ (row & 15))) * 8;   // 64 x 128 bf16 chunk
}
__device__ __forceinline__ int swz32(int row, int g) {
    return (row * 32 + (g ^ (row & 31))) * 8;   // 64 x 256 bf16 tile
}

// W fp32 -> hi/lo bf16 planes. 64 blocks x 256 threads x 4 elems.
__global__ __launch_bounds__(256) void convw_kernel(
    const float* __restrict__ W, __bf16* __restrict__ Wh, __bf16* __restrict__ Wl) {
    int idx = blockIdx.x * 256 + threadIdx.x;  // 0..16383
    float4 v = ((const float4*)W)[idx];
    float f[4] = {v.x, v.y, v.z, v.w};
    union { __bf16 b[4]; uint2 u; } H, L;
#pragma unroll
    for (int k = 0; k < 4; ++k) {
        __bf16 h = (__bf16)f[k];
        H.b[k] = h;
        L.b[k] = (__bf16)(f[k] - (float)h);
    }
    *(uint2*)&Wh[idx * 4] = H.u;
    *(uint2*)&Wl[idx * 4] = L.u;
}

// Fused: convert X rows -> Xh/Xl global (+ LDS), then P = X @ W^T (split-3),
// emit Ph/Pl. One block per 64-row tile (128 blocks).
// A-frags preloaded in registers (64 VGPRs); W-frags streamed from L2.
__global__ __launch_bounds__(256, 2) void prep_kernel(
    const float* __restrict__ Xf,
    const __bf16* __restrict__ Wh, const __bf16* __restrict__ Wl,
    __bf16* __restrict__ XhG, __bf16* __restrict__ XlG,
    __bf16* __restrict__ Ph, __bf16* __restrict__ Pl) {
    __shared__ __align__(16) __bf16 sXh[64 * 256];
    __shared__ __align__(16) __bf16 sXl[64 * 256];
    const int tid = threadIdx.x, rb = blockIdx.x;
    const float* src = Xf + rb * 64 * 256;
#pragma unroll
    for (int it = 0; it < 8; ++it) {
        int idx = it * 256 + tid;           // 2048 granules
        int row = idx >> 5, g = idx & 31;
        const float* p = src + row * 256 + g * 8;
        float4 v0 = *(const float4*)p;
        float4 v1 = *(const float4*)(p + 4);
        float f[8] = {v0.x, v0.y, v0.z, v0.w, v1.x, v1.y, v1.z, v1.w};
        union { __bf16 b[8]; uint4 u; } H, L;
#pragma unroll
        for (int k = 0; k < 8; ++k) {
            __bf16 h = (__bf16)f[k];
            H.b[k] = h;
            L.b[k] = (__bf16)(f[k] - (float)h);
        }
        int go = rb * 16384 + row * 256 + g * 8;
        *(uint4*)&XhG[go] = H.u;
        *(uint4*)&XlG[go] = L.u;
        int o = swz32(row, g);
        *(uint4*)&sXh[o] = H.u;
        *(uint4*)&sXl[o] = L.u;
    }
    __syncthreads();

    const int lane = tid & 63, wave = tid >> 6, m = lane & 15, quad = lane >> 4;
    const int arow = wave * 16 + m;
    bf16x8 Ah[8], Al[8];
#pragma unroll
    for (int k0 = 0; k0 < 8; ++k0) {
        int o = swz32(arow, k0 * 4 + quad);
        Ah[k0] = *(const bf16x8*)&sXh[o];
        Al[k0] = *(const bf16x8*)&sXl[o];
    }
    const f32x4 z = {0.f, 0.f, 0.f, 0.f};
#pragma unroll
    for (int ng = 0; ng < 4; ++ng) {
        f32x4 acc[4];
#pragma unroll
        for (int n = 0; n < 4; ++n) acc[n] = z;
#pragma unroll
        for (int k0 = 0; k0 < 8; ++k0) {
#pragma unroll
            for (int n = 0; n < 4; ++n) {
                int g = ng * 64 + n * 16 + m;
                int wo = g * 256 + k0 * 32 + quad * 8;
                bf16x8 bh = *(const bf16x8*)&Wh[wo];
                bf16x8 bl = *(const bf16x8*)&Wl[wo];
                acc[n] = __builtin_amdgcn_mfma_f32_16x16x32_bf16(Ah[k0], bh, acc[n], 0, 0, 0);
                acc[n] = __builtin_amdgcn_mfma_f32_16x16x32_bf16(Ah[k0], bl, acc[n], 0, 0, 0);
                acc[n] = __builtin_amdgcn_mfma_f32_16x16x32_bf16(Al[k0], bh, acc[n], 0, 0, 0);
            }
        }
#pragma unroll
        for (int n = 0; n < 4; ++n)
#pragma unroll
            for (int r = 0; r < 4; ++r) {
                int row = rb * 64 + wave * 16 + quad * 4 + r;
                int col = ng * 64 + n * 16 + m;
                float v = acc[n][r];
                __bf16 h = (__bf16)v;
                Ph[row * 256 + col] = h;
                Pl[row * 256 + col] = (__bf16)(v - (float)h);
            }
    }
}

// One block per (b, i, j-pair). P(b,i)-fragments live in registers the whole
// kernel; X(b,j) hi/lo staged per K=128 chunk (33.3 KB LDS -> 4 blocks/CU).
__global__ __launch_bounds__(256, 4) void main_kernel(
    const float* __restrict__ Xf, const float* __restrict__ maskf,
    const float* __restrict__ aselff,
    const __bf16* __restrict__ XhG, const __bf16* __restrict__ XlG,
    const __bf16* __restrict__ Ph, const __bf16* __restrict__ Pl,
    float* __restrict__ out) {
    __shared__ __align__(16) __bf16 sXh[64 * 128];
    __shared__ __align__(16) __bf16 sXl[64 * 128];
    __shared__ float sWpart[4 * 64];
    __shared__ float s_w[64];
    const int tid = threadIdx.x;
    const int jp = blockIdx.x & 15;
    const int i = (blockIdx.x >> 4) & 31;
    const int b = blockIdx.x >> 9;
    const int lane = tid & 63, wave = tid >> 6, m = lane & 15, quad = lane >> 4;

    // A fragments: P rows wave*16+m, full K=256, hi/lo (64 VGPRs).
    const int prow = ((b * 32 + i) * 64 + wave * 16 + m) * 256;
    bf16x8 Ah[8], Al[8];
#pragma unroll
    for (int k0 = 0; k0 < 8; ++k0) {
        Ah[k0] = *(const bf16x8*)&Ph[prow + k0 * 32 + quad * 8];
        Al[k0] = *(const bf16x8*)&Pl[prow + k0 * 32 + quad * 8];
    }
    const float4 aself4 = *(const float4*)&aselff[(b * 32 + i) * 64 + wave * 16 + quad * 4];
    const f32x4 z = {0.f, 0.f, 0.f, 0.f};

#pragma unroll
    for (int jt = 0; jt < 2; ++jt) {
        const int j = jp * 2 + jt;
        const int xbase = (b * 32 + j) * 64 * 256;
        f32x4 acc[4];
#pragma unroll
        for (int n = 0; n < 4; ++n) acc[n] = z;

#pragma unroll
        for (int kc = 0; kc < 2; ++kc) {
            if (jt | kc) __syncthreads();  // prior readers done before restage
#pragma unroll
            for (int it = 0; it < 4; ++it) {
                int idx = it * 256 + tid;   // 1024 granules
                int row = idx >> 4, g = idx & 15;
                int go = xbase + row * 256 + kc * 128 + g * 8;
                int o = swz16(row, g);
                *(uint4*)&sXh[o] = *(const uint4*)&XhG[go];
                *(uint4*)&sXl[o] = *(const uint4*)&XlG[go];
            }
            __syncthreads();
#pragma unroll
            for (int k0 = 0; k0 < 4; ++k0) {
                const int ak = kc * 4 + k0;
#pragma unroll
                for (int n = 0; n < 4; ++n) {
                    int bo = swz16(n * 16 + m, k0 * 4 + quad);
                    bf16x8 bh = *(const bf16x8*)&sXh[bo];
                    bf16x8 bl = *(const bf16x8*)&sXl[bo];
                    acc[n] = __builtin_amdgcn_mfma_f32_16x16x32_bf16(Ah[ak], bh, acc[n], 0, 0, 0);
                    acc[n] = __builtin_amdgcn_mfma_f32_16x16x32_bf16(Ah[ak], bl, acc[n], 0, 0, 0);
                    acc[n] = __builtin_amdgcn_mfma_f32_16x16x32_bf16(Al[ak], bh, acc[n], 0, 0, 0);
                }
            }
        }

        // Epilogue: sigmoid -> att store; w[t] = sum_s aself[s]*att[s,t] via
        // in-wave shuffle + 1 KB LDS; fused[h] = sum_t w[t]*X[t,h].
        const float* mrow = maskf + (b * 32 + j) * 64;
        float* outA = out + FUSED_N + ((size_t)((b * 32 + i) * 32 + j)) * 4096;
        float part[4];
#pragma unroll
        for (int n = 0; n < 4; ++n) {
            const int t = n * 16 + m;
            const float madd = (1.0f - mrow[t]) * NEG_BIG;
            float p = 0.f;
#pragma unroll
            for (int r = 0; r < 4; ++r) {
                const int s = wave * 16 + quad * 4 + r;
                float x = acc[n][r] + madd;
                float a = 1.0f / (1.0f + __expf(-x));
                outA[s * 64 + t] = a;
                p += ((const float*)&aself4)[r] * a;
            }
            part[n] = p;
        }
#pragma unroll
        for (int n = 0; n < 4; ++n) {  // reduce over quad (lanes quad*16+m)
            part[n] += __shfl_xor(part[n], 16, 64);
            part[n] += __shfl_xor(part[n], 32, 64);
        }
        if (quad == 0) {
#pragma unroll
            for (int n = 0; n < 4; ++n) sWpart[wave * 64 + n * 16 + m] = part[n];
        }
        __syncthreads();
        if (tid < 64)
            s_w[tid] = sWpart[tid] + sWpart[64 + tid] + sWpart[128 + tid] + sWpart[192 + tid];
        __syncthreads();

        const float* Xg = Xf + xbase;
        float acf = 0.f;
#pragma unroll
        for (int t = 0; t < 64; ++t) acf += s_w[t] * Xg[t * 256 + tid];
        out[((size_t)((b * 32 + i) * 32 + j)) * 256 + tid] = acf;
    }
}

extern "C" void kernel_launch(void* const* d_in, const int* in_sizes, int n_in,
                              void* d_out, int out_size, void* d_ws, size_t ws_size,
                              hipStream_t stream) {
    const float* X     = (const float*)d_in[0];  // [4,32,64,256] fp32
    const float* mask  = (const float*)d_in[1];  // [4,32,64]
    const float* aself = (const float*)d_in[2];  // [4,32,64]
    const float* W     = (const float*)d_in[3];  // [256,256]
    float* out = (float*)d_out;

    __bf16* ws = (__bf16*)d_ws;
    const size_t NX = 2097152, NW = 65536;
    __bf16* Xh = ws;
    __bf16* Xl = Xh + NX;
    __bf16* Ph = Xl + NX;
    __bf16* Pl = Ph + NX;
    __bf16* Wh = Pl + NX;
    __bf16* Wl = Wh + NW;

    convw_kernel<<<dim3(64), dim3(256), 0, stream>>>(W, Wh, Wl);
    prep_kernel<<<dim3(128), dim3(256), 0, stream>>>(X, Wh, Wl, Xh, Xl, Ph, Pl);
    main_kernel<<<dim3(2048), dim3(256), 0, stream>>>(
        X, mask, aself, Xh, Xl, Ph, Pl, out);
}

// Round 4
// 160.837 us; speedup vs baseline: 1.2156x; 1.2156x over previous
//
#include <hip/hip_runtime.h>
#include <hip/hip_bf16.h>

typedef __bf16 bf16x8 __attribute__((ext_vector_type(8)));
typedef float  f32x4  __attribute__((ext_vector_type(4)));

#define NEG_BIG (-1e10f)

constexpr int FUSED_N = 4 * 32 * 32 * 256;  // 1048576

// ---------------------------------------------------------------------------
// fp32 inputs, no fp32 MFMA on CDNA4: split x = hi + lo (bf16 RNE + residual),
// scores ~= Ah*Bh + Ah*Bl + Al*Bh (drop lo*lo, ~2^-18 rel). Verified r2.
// r3 lesson: launch_bounds(256,4) -> 64 VGPRs -> scratch spills (+54 MB HBM
// writes). A-frags alone need 64 VGPRs; use (256,3) and async LDS staging.
// ---------------------------------------------------------------------------

// 16B-granule XOR swizzle for a 64row x 16granule (64x128 bf16) chunk.
// slot(row,g) holds granule g of row; returns ELEMENT offset.
__device__ __forceinline__ int swz16(int row, int g) {
    return (row * 16 + (g ^ (row & 15))) * 8;
}
// 32row x 32granule (32x256 bf16) tile for prep.
__device__ __forceinline__ int swz32r(int row, int g) {
    return (row * 32 + (g ^ row)) * 8;   // row in [0,32)
}

// Async 16B global->LDS (DMA, no VGPR round trip). LDS dest must be
// wave-uniform base; lane L lands at base + 16*L.
__device__ __forceinline__ void async_ld16(const void* g, void* l) {
    __builtin_amdgcn_global_load_lds(
        (const __attribute__((address_space(1))) void*)g,
        (__attribute__((address_space(3))) void*)l, 16, 0, 0);
}

// ---------------------------------------------------------------------------
// prep: convert X -> Xh/Xl planes (global) and compute P = X @ W^T (split-3)
// -> Ph/Pl planes. One block per 32-row tile of X (256 blocks).
// W is read as fp32 and split in-register (no separate convert kernel).
// ---------------------------------------------------------------------------
__global__ __launch_bounds__(256, 2) void prep_kernel(
    const float* __restrict__ Xf, const float* __restrict__ Wf,
    __bf16* __restrict__ XhG, __bf16* __restrict__ XlG,
    __bf16* __restrict__ Ph, __bf16* __restrict__ Pl) {
    __shared__ __align__(16) __bf16 sXh[32 * 256];   // 16 KB
    __shared__ __align__(16) __bf16 sXl[32 * 256];   // 16 KB
    const int tid = threadIdx.x, rb = blockIdx.x;    // rows rb*32..rb*32+31

    // Stage + convert 32x256 fp32 -> hi/lo (LDS swizzled + global linear).
#pragma unroll
    for (int it = 0; it < 4; ++it) {
        int idx = it * 256 + tid;          // 1024 granules
        int row = idx >> 5, g = idx & 31;
        const float* p = Xf + (rb * 32 + row) * 256 + g * 8;
        float4 v0 = *(const float4*)p;
        float4 v1 = *(const float4*)(p + 4);
        float f[8] = {v0.x, v0.y, v0.z, v0.w, v1.x, v1.y, v1.z, v1.w};
        union { __bf16 b[8]; uint4 u; } H, L;
#pragma unroll
        for (int k = 0; k < 8; ++k) {
            __bf16 h = (__bf16)f[k];
            H.b[k] = h;
            L.b[k] = (__bf16)(f[k] - (float)h);
        }
        int go = (rb * 32 + row) * 256 + g * 8;
        *(uint4*)&XhG[go] = H.u;
        *(uint4*)&XlG[go] = L.u;
        int o = swz32r(row, g);
        *(uint4*)&sXh[o] = H.u;
        *(uint4*)&sXl[o] = L.u;
    }
    __syncthreads();

    const int lane = tid & 63, wave = tid >> 6, m = lane & 15, quad = lane >> 4;
    const int rhalf = wave & 1;            // which 16 rows
    const int ngbase = (wave >> 1) * 2;    // which 2 of 4 col groups
    const int arow = rhalf * 16 + m;

    bf16x8 Ah[8], Al[8];
#pragma unroll
    for (int k0 = 0; k0 < 8; ++k0) {
        int o = swz32r(arow, k0 * 4 + quad);
        Ah[k0] = *(const bf16x8*)&sXh[o];
        Al[k0] = *(const bf16x8*)&sXl[o];
    }
    const f32x4 z = {0.f, 0.f, 0.f, 0.f};
#pragma unroll
    for (int ngo = 0; ngo < 2; ++ngo) {
        const int ng = ngbase + ngo;
        f32x4 acc[4];
#pragma unroll
        for (int n = 0; n < 4; ++n) acc[n] = z;
#pragma unroll
        for (int k0 = 0; k0 < 8; ++k0) {
#pragma unroll
            for (int n = 0; n < 4; ++n) {
                const int g = ng * 64 + n * 16 + m;
                const float* wp = Wf + g * 256 + k0 * 32 + quad * 8;
                float4 w0 = *(const float4*)wp;
                float4 w1 = *(const float4*)(wp + 4);
                float wf[8] = {w0.x, w0.y, w0.z, w0.w, w1.x, w1.y, w1.z, w1.w};
                union { __bf16 b[8]; bf16x8 v; } BH, BL;
#pragma unroll
                for (int k = 0; k < 8; ++k) {
                    __bf16 h = (__bf16)wf[k];
                    BH.b[k] = h;
                    BL.b[k] = (__bf16)(wf[k] - (float)h);
                }
                acc[n] = __builtin_amdgcn_mfma_f32_16x16x32_bf16(Ah[k0], BH.v, acc[n], 0, 0, 0);
                acc[n] = __builtin_amdgcn_mfma_f32_16x16x32_bf16(Ah[k0], BL.v, acc[n], 0, 0, 0);
                acc[n] = __builtin_amdgcn_mfma_f32_16x16x32_bf16(Al[k0], BH.v, acc[n], 0, 0, 0);
            }
        }
#pragma unroll
        for (int n = 0; n < 4; ++n)
#pragma unroll
            for (int r = 0; r < 4; ++r) {
                int row = rb * 32 + rhalf * 16 + quad * 4 + r;
                int col = ng * 64 + n * 16 + m;
                float v = acc[n][r];
                __bf16 h = (__bf16)v;
                Ph[row * 256 + col] = h;
                Pl[row * 256 + col] = (__bf16)(v - (float)h);
            }
    }
}

// ---------------------------------------------------------------------------
// main: one block per (b,i,j). P(b,i) fragments in registers (64 VGPRs);
// X(b,j) hi/lo staged per K=128 chunk via async global_load_lds with
// swizzle-inverted source gather (LDS slot base+16L is fixed; we fetch the
// granule that belongs there). 33.25 KB LDS -> 3-4 blocks/CU.
// ---------------------------------------------------------------------------
__global__ __launch_bounds__(256, 3) void main_kernel(
    const float* __restrict__ Xf, const float* __restrict__ maskf,
    const float* __restrict__ aselff,
    const __bf16* __restrict__ XhG, const __bf16* __restrict__ XlG,
    const __bf16* __restrict__ Ph, const __bf16* __restrict__ Pl,
    float* __restrict__ out) {
    __shared__ __align__(16) __bf16 sXh[64 * 128];   // 16 KB
    __shared__ __align__(16) __bf16 sXl[64 * 128];   // 16 KB
    __shared__ float sWpart[4 * 64];                 // 1 KB
    __shared__ float s_w[64];
    const int tid = threadIdx.x;
    const int j = blockIdx.x & 31;
    const int i = (blockIdx.x >> 5) & 31;
    const int b = blockIdx.x >> 10;
    const int lane = tid & 63, wave = tid >> 6, m = lane & 15, quad = lane >> 4;
    const int xbase = (b * 32 + j) * 64 * 256;

    // Async stage of one K=128 chunk (hi+lo): wave w issues insts ii=4w..4w+3,
    // inst ii covers rows ii*4+quad, lane slot gg=m holds granule gg^(row&15).
    auto stage = [&](int kc) {
#pragma unroll
        for (int it = 0; it < 4; ++it) {
            const int ii = wave * 4 + it;
            const int row = ii * 4 + quad;
            const int g = m ^ (row & 15);
            const int go = xbase + row * 256 + kc * 128 + g * 8;
            async_ld16(&XhG[go], &sXh[ii * 512]);
            async_ld16(&XlG[go], &sXl[ii * 512]);
        }
    };

    stage(0);  // in flight while A-frags load

    // A fragments: P rows wave*16+m, full K=256, hi/lo (64 VGPRs).
    const int prow = ((b * 32 + i) * 64 + wave * 16 + m) * 256;
    bf16x8 Ah[8], Al[8];
#pragma unroll
    for (int k0 = 0; k0 < 8; ++k0) {
        Ah[k0] = *(const bf16x8*)&Ph[prow + k0 * 32 + quad * 8];
        Al[k0] = *(const bf16x8*)&Pl[prow + k0 * 32 + quad * 8];
    }
    const float4 aself4 = *(const float4*)&aselff[(b * 32 + i) * 64 + wave * 16 + quad * 4];
    const float* mrow = maskf + (b * 32 + j) * 64;
    float madd[4];
#pragma unroll
    for (int n = 0; n < 4; ++n) madd[n] = (1.0f - mrow[n * 16 + m]) * NEG_BIG;

    f32x4 acc[4];
    const f32x4 z = {0.f, 0.f, 0.f, 0.f};
#pragma unroll
    for (int n = 0; n < 4; ++n) acc[n] = z;

#pragma unroll
    for (int kc = 0; kc < 2; ++kc) {
        if (kc) {
            __syncthreads();   // chunk0 reads done
            stage(1);
        }
        __syncthreads();       // staging drained (vmcnt(0) at barrier)
#pragma unroll
        for (int k0 = 0; k0 < 4; ++k0) {
            const int ak = kc * 4 + k0;
#pragma unroll
            for (int n = 0; n < 4; ++n) {
                const int bo = swz16(n * 16 + m, k0 * 4 + quad);
                bf16x8 bh = *(const bf16x8*)&sXh[bo];
                bf16x8 bl = *(const bf16x8*)&sXl[bo];
                acc[n] = __builtin_amdgcn_mfma_f32_16x16x32_bf16(Ah[ak], bh, acc[n], 0, 0, 0);
                acc[n] = __builtin_amdgcn_mfma_f32_16x16x32_bf16(Ah[ak], bl, acc[n], 0, 0, 0);
                acc[n] = __builtin_amdgcn_mfma_f32_16x16x32_bf16(Al[ak], bh, acc[n], 0, 0, 0);
            }
        }
    }

    // Epilogue: sigmoid -> att (fp32); w[t] = sum_s aself[s]*att[s,t];
    // fused[h] = sum_t w[t]*X[t,h].
    float* outA = out + FUSED_N + ((size_t)((b * 32 + i) * 32 + j)) * 4096;
    float part[4];
#pragma unroll
    for (int n = 0; n < 4; ++n) {
        const int t = n * 16 + m;
        float p = 0.f;
#pragma unroll
        for (int r = 0; r < 4; ++r) {
            const int s = wave * 16 + quad * 4 + r;
            float x = acc[n][r] + madd[n];
            float a = 1.0f / (1.0f + __expf(-x));
            outA[s * 64 + t] = a;
            p += ((const float*)&aself4)[r] * a;
        }
        part[n] = p;
    }
#pragma unroll
    for (int n = 0; n < 4; ++n) {   // reduce over quad (lanes quad*16+m)
        part[n] += __shfl_xor(part[n], 16, 64);
        part[n] += __shfl_xor(part[n], 32, 64);
    }
    if (quad == 0) {
#pragma unroll
        for (int n = 0; n < 4; ++n) sWpart[wave * 64 + n * 16 + m] = part[n];
    }
    __syncthreads();
    if (tid < 64)
        s_w[tid] = sWpart[tid] + sWpart[64 + tid] + sWpart[128 + tid] + sWpart[192 + tid];
    __syncthreads();

    const float* Xg = Xf + xbase;
    float acf = 0.f;
#pragma unroll 16
    for (int t = 0; t < 64; ++t) acf += s_w[t] * Xg[t * 256 + tid];
    out[((size_t)((b * 32 + i) * 32 + j)) * 256 + tid] = acf;
}

extern "C" void kernel_launch(void* const* d_in, const int* in_sizes, int n_in,
                              void* d_out, int out_size, void* d_ws, size_t ws_size,
                              hipStream_t stream) {
    const float* X     = (const float*)d_in[0];  // [4,32,64,256] fp32
    const float* mask  = (const float*)d_in[1];  // [4,32,64]
    const float* aself = (const float*)d_in[2];  // [4,32,64]
    const float* W     = (const float*)d_in[3];  // [256,256]
    float* out = (float*)d_out;

    __bf16* ws = (__bf16*)d_ws;
    const size_t NX = 2097152;
    __bf16* Xh = ws;
    __bf16* Xl = Xh + NX;
    __bf16* Ph = Xl + NX;
    __bf16* Pl = Ph + NX;

    prep_kernel<<<dim3(256), dim3(256), 0, stream>>>(X, W, Xh, Xl, Ph, Pl);
    main_kernel<<<dim3(4096), dim3(256), 0, stream>>>(
        X, mask, aself, Xh, Xl, Ph, Pl, out);
}